// Round 14
// baseline (753.900 us; speedup 1.0000x reference)
//
#include <hip/hip_runtime.h>

#define B_ 256
#define T_ 128
#define E_ 512
#define H_ 512
#define NG 2048   // 4*H_
#define NB 256    // persistent blocks
#define NT 512    // threads per block (8 waves)

typedef __attribute__((ext_vector_type(8))) short bf16x8;
typedef __attribute__((ext_vector_type(4))) float f32x4;
typedef unsigned long long u64;

__device__ __forceinline__ short f2bf(float f) {
  union { float f; unsigned u; } x; x.f = f;
  unsigned r = x.u + 0x7FFFu + ((x.u >> 16) & 1u);  // RNE
  return (short)(r >> 16);
}
__device__ __forceinline__ float bf2f(short s) {
  union { unsigned u; float f; } x;
  x.u = ((unsigned)(unsigned short)s) << 16; return x.f;
}
__device__ __forceinline__ float sigm(float x) { return 1.0f / (1.0f + __expf(-x)); }
__device__ __forceinline__ float tanh_(float x) {
  float cx = fminf(fmaxf(x, -9.f), 9.f);
  float e = __expf(2.f * cx);
  return (e - 1.f) / (e + 1.f);
}

// ---- Wt[j][k] = bf16( k<512 ? Wx[k][j] : Uh[k-512][j] )
__global__ __launch_bounds__(256) void prep_w(const float* __restrict__ Wx,
                                              const float* __restrict__ Uh,
                                              short* __restrict__ Wt) {
  __shared__ float tile[64][65];
  const int k0 = blockIdx.x * 64;   // 16 blocks
  const int j0 = blockIdx.y * 64;   // 32 blocks
  const int tx = threadIdx.x & 63, ty = threadIdx.x >> 6;
#pragma unroll
  for (int r = 0; r < 16; ++r) {
    int k = k0 + r * 4 + ty;
    float v = (k < 512) ? Wx[(size_t)k * NG + j0 + tx]
                        : Uh[(size_t)(k - 512) * NG + j0 + tx];
    tile[r * 4 + ty][tx] = v;
  }
  __syncthreads();
#pragma unroll
  for (int r = 0; r < 16; ++r) {
    int j = j0 + r * 4 + ty;
    Wt[(size_t)j * 1024 + k0 + tx] = f2bf(tile[tx][r * 4 + ty]);
  }
}

// ---- xs[t][b][e] = bf16(emb[captions[b][t]][e]); padding_idx=0 row zeroed
__global__ __launch_bounds__(256) void stage_x(const int* __restrict__ captions,
                                               const float* __restrict__ emb,
                                               short* __restrict__ xs) {
  const int bid = blockIdx.x;          // = t*B_ + b
  const int t = bid >> 8, b = bid & 255;
  const int tok = captions[b * T_ + t];
  short* o = xs + (size_t)bid * E_;
  const float* src = emb + (size_t)tok * E_;
  int e0 = threadIdx.x, e1 = threadIdx.x + 256;
  if (tok) { o[e0] = f2bf(src[e0]); o[e1] = f2bf(src[e1]); }
  else     { o[e0] = 0;             o[e1] = 0; }
}

// ---- persistent kernel: all 128 LSTM steps.
// Topology: mg = bid>>5 (groups span all 8 XCDs), jt = bid&31. Protocol: R10's
// proven ack-gated flags (store h -> vmcnt(0) -> flag; one 128-B line/flag).
// NEW STRUCTURE: publisher/reader wave split. Waves (kq,mh), kq=wid>>1.
//  Phase A (all): kq0/1 x-MFMA; kq2/3 poll 32 flags (2 pub waves x 16 blocks
//  of their k-slice) then bulk-load h_{t-1} + MFMA. ALL waves write their
//  f32x4 partials to parity LDS slot [kq]. lgkmcnt(0); raw s_barrier.
//  Phase B (kq0/1 only = publishers): each handles 8 rows x 16 cols of its mh
//  (rows mh*16+kq*8..+8): reduce 4 slots from LDS, gates (c in regs, 2/lane),
//  pack+store h, vmcnt(0), per-wave flag. Readers go STRAIGHT from barrier to
//  t+1 polling — own-block publish is off the reader critical path.
// Safety (2 buffers): flag=t+1 from Y => Y passed barrier(t) => Y's readers
// consumed h_{t-1}; X overwrites h_{t-1}'s buffer only in phase B(t+1), after
// its kq2 AND kq3 saw all 32 blocks' flags >= t+1 (barrier-ordered).
// Flags zeroed every launch (gate all h reads; graph-replay safe).
__global__ __launch_bounds__(NT, 2) void lstm_all(
    const short* __restrict__ xs,   // [T][B][E] bf16
    const short* __restrict__ Wt,   // [2048][1024] bf16
    const float* __restrict__ bx, const float* __restrict__ bu,
    unsigned* __restrict__ hb0, unsigned* __restrict__ hb1,
    unsigned* __restrict__ flags) { // [8 mg][4 pub][32 jt] stride 32 uints
  // [parity][slot=kq][mh][gate][l4][l15] of f32x4 -> 64 KB
  __shared__ f32x4 part[2][4][2][4][4][16];

  const int tid = threadIdx.x;
  const int wid = tid >> 6, lane = tid & 63;
  const int l15 = lane & 15, l4 = lane >> 4;
  const int kq = wid >> 1, mh = wid & 1;
  const int mg = blockIdx.x >> 5, jt = blockIdx.x & 31;   // cross-XCD groups
  const int j0 = jt * 16;
  const int rA = mg * 32 + mh * 16 + l15;

  // ---- persistent B fragments, pinned on-chip (VGPR/AGPR)
  bf16x8 bfr[4][8];
#pragma unroll
  for (int g = 0; g < 4; ++g) {
    const short* wp = Wt + (size_t)(g * 512 + j0 + l15) * 1024 + kq * 256 + l4 * 8;
#pragma unroll
    for (int ks = 0; ks < 8; ++ks)
      bfr[g][ks] = *(const bf16x8*)(wp + ks * 32);
  }
#pragma unroll
  for (int g = 0; g < 4; ++g)
#pragma unroll
    for (int ks = 0; ks < 8; ++ks)
      asm volatile("" : "+v"(bfr[g][ks]));   // sever rematerialization

  // ---- publisher constants (kq<2): lane owns col J, rows mh*16+kq*8+l4*2+{0,1}
  const int J = j0 + l15;
  const float bi  = bx[J] + bu[J];
  const float bf_ = bx[512 + J] + bu[512 + J];
  const float bo  = bx[1024 + J] + bu[1024 + J];
  const float bg  = bx[1536 + J] + bu[1536 + J];
  float c_reg[2] = {0.f, 0.f};

  unsigned* fl = flags + mg * 4 * 32 * 32;  // flag (pub,jt) at fl[(pub*32+jt)*32]

  for (int t = 0; t < T_; ++t) {
    const int tp = t & 1;
    unsigned* hout = tp ? hb1 : hb0;
    const unsigned* hin = tp ? hb0 : hb1;   // h_{t-1} in buffer (t-1)&1

    f32x4 acc[4] = {{0,0,0,0},{0,0,0,0},{0,0,0,0},{0,0,0,0}};

    if (kq < 2) {
      // ---- x half of K (always ready)
      const short* ab = xs + ((size_t)t * B_ + rA) * E_ + kq * 256 + l4 * 8;
      bf16x8 af[8];
#pragma unroll
      for (int ks = 0; ks < 8; ++ks) af[ks] = *(const bf16x8*)(ab + ks * 32);
#pragma unroll
      for (int ks = 0; ks < 8; ++ks)
#pragma unroll
        for (int g = 0; g < 4; ++g)
          acc[g] = __builtin_amdgcn_mfma_f32_16x16x32_bf16(af[ks], bfr[g][ks], acc[g], 0, 0, 0);
    } else if (t > 0) {
      // ---- poll the 32 publisher flags of this (k-slice, mh): 2 pubs x 16 jt
      const unsigned thr = (unsigned)t;
      const int jtp = (lane & 15) + (kq - 2) * 16;
      const int pub = ((lane >> 4) & 1) * 2 + mh;     // pubs {mh, 2+mh}
      const unsigned* myfl = fl + (pub * 32 + jtp) * 32;
      unsigned v = __hip_atomic_load(myfl, __ATOMIC_RELAXED, __HIP_MEMORY_SCOPE_AGENT);
      int spin = 0;
      while (!__all((int)(v >= thr))) {
        if (spin++ < 4) __builtin_amdgcn_s_sleep(1);
        else            __builtin_amdgcn_s_sleep(8);
        v = __hip_atomic_load(myfl, __ATOMIC_RELAXED, __HIP_MEMORY_SCOPE_AGENT);
      }
      asm volatile("" ::: "memory");
      // ---- one bulk load pass (flags are ack-gated: data valid), then MFMA
      const u64* hp = (const u64*)hin + (size_t)rA * 128 + (kq - 2) * 64 + l4 * 2;
      u64 w[16];
#pragma unroll
      for (int ks = 0; ks < 8; ++ks) {
        w[ks * 2]     = __hip_atomic_load(hp + ks * 8,     __ATOMIC_RELAXED, __HIP_MEMORY_SCOPE_AGENT);
        w[ks * 2 + 1] = __hip_atomic_load(hp + ks * 8 + 1, __ATOMIC_RELAXED, __HIP_MEMORY_SCOPE_AGENT);
      }
#pragma unroll
      for (int ks = 0; ks < 8; ++ks) {
        union { bf16x8 v; unsigned u[4]; } fa;
        fa.u[0] = (unsigned)w[ks * 2];
        fa.u[1] = (unsigned)(w[ks * 2] >> 32);
        fa.u[2] = (unsigned)w[ks * 2 + 1];
        fa.u[3] = (unsigned)(w[ks * 2 + 1] >> 32);
#pragma unroll
        for (int g = 0; g < 4; ++g)
          acc[g] = __builtin_amdgcn_mfma_f32_16x16x32_bf16(fa.v, bfr[g][ks], acc[g], 0, 0, 0);
      }
    }
    // (kq>=2, t==0: acc stays 0 -> zero partials, correct for h_{-1}=0)

    // ---- ALL waves write their partial (one ds_write_b128 per gate)
#pragma unroll
    for (int g = 0; g < 4; ++g)
      part[tp][kq][mh][g][l4][l15] = acc[g];
    asm volatile("s_waitcnt lgkmcnt(0)" ::: "memory");
    __builtin_amdgcn_s_barrier();               // raw barrier: no vmcnt drain

    // ---- phase B: kq0/1 publish; kq2/3 go straight to t+1 polling
    if (kq < 2) {
      unsigned hw[2];
#pragma unroll
      for (int r = 0; r < 2; ++r) {
        const int Rm = kq * 8 + l4 * 2 + r;       // row within this mh's 16
        const int ri = Rm >> 2, rc = Rm & 3;
        float sums[4];
#pragma unroll
        for (int g = 0; g < 4; ++g)
          sums[g] = part[tp][0][mh][g][ri][l15][rc]
                  + part[tp][1][mh][g][ri][l15][rc]
                  + part[tp][2][mh][g][ri][l15][rc]
                  + part[tp][3][mh][g][ri][l15][rc];
        float iv = sums[0] + bi, fv = sums[1] + bf_;
        float ov = sums[2] + bo, gv = sums[3] + bg;
        float cn = sigm(fv) * c_reg[r] + sigm(iv) * tanh_(gv);
        c_reg[r] = cn;
        hw[r] = (unsigned)(unsigned short)f2bf(sigm(ov) * tanh_(cn));
      }
#pragma unroll
      for (int r = 0; r < 2; ++r) {
        unsigned other = (unsigned)__shfl_xor((int)hw[r], 1, 64);
        if (!(l15 & 1)) {
          const int R = mg * 32 + mh * 16 + kq * 8 + l4 * 2 + r;
          __hip_atomic_store(hout + (size_t)R * 256 + (J >> 1),
                             hw[r] | (other << 16),
                             __ATOMIC_RELAXED, __HIP_MEMORY_SCOPE_AGENT);
        }
      }
      // ACK then flag: readers that see the flag see the data (R10 protocol).
      asm volatile("s_waitcnt vmcnt(0)" ::: "memory");
      if (lane == 0)
        __hip_atomic_store(fl + ((kq * 2 + mh) * 32 + jt) * 32, (unsigned)(t + 1),
                           __ATOMIC_RELAXED, __HIP_MEMORY_SCOPE_AGENT);
    }
  }
}

// ---- out[b,:] = normalize( h_last[b,:] @ fcW + fcb ); h is packed u32{2xbf16}
__global__ __launch_bounds__(256) void final_fc(const unsigned* __restrict__ h,
                                                const float* __restrict__ fcW,
                                                const float* __restrict__ fcb,
                                                float* __restrict__ out) {
  const int b = blockIdx.x, tid = threadIdx.x;
  __shared__ float hrow[512];
  __shared__ float red[256];
  {
    unsigned w = h[(size_t)b * 256 + tid];
    hrow[tid * 2]     = bf2f((short)(w & 0xFFFF));
    hrow[tid * 2 + 1] = bf2f((short)(w >> 16));
  }
  __syncthreads();
  float a0 = fcb[tid], a1 = fcb[tid + 256];
  for (int k = 0; k < 512; ++k) {
    float hv = hrow[k];
    a0 += hv * fcW[(size_t)k * 512 + tid];
    a1 += hv * fcW[(size_t)k * 512 + tid + 256];
  }
  red[tid] = a0 * a0 + a1 * a1;
  __syncthreads();
  for (int s = 128; s > 0; s >>= 1) {
    if (tid < s) red[tid] += red[tid + s];
    __syncthreads();
  }
  float scale = 1.0f / fmaxf(sqrtf(red[0]), 1e-12f);
  out[(size_t)b * 512 + tid] = a0 * scale;
  out[(size_t)b * 512 + tid + 256] = a1 * scale;
}

extern "C" void kernel_launch(void* const* d_in, const int* in_sizes, int n_in,
                              void* d_out, int out_size, void* d_ws, size_t ws_size,
                              hipStream_t stream) {
  const int*   captions = (const int*)d_in[0];
  const float* emb      = (const float*)d_in[1];
  const float* Wx       = (const float*)d_in[2];
  const float* bx       = (const float*)d_in[3];
  const float* Uh       = (const float*)d_in[4];
  const float* bu       = (const float*)d_in[5];
  const float* fcW      = (const float*)d_in[6];
  const float* fcb      = (const float*)d_in[7];
  float* out = (float*)d_out;

  char* ws = (char*)d_ws;
  size_t off = 0;
  auto alloc = [&](size_t bytes) {
    char* p = ws + off;
    off += (bytes + 255) & ~(size_t)255;
    return p;
  };
  short*    Wt    = (short*)alloc((size_t)NG * 1024 * 2);     // 4 MB
  short*    xs    = (short*)alloc((size_t)T_ * B_ * E_ * 2);  // 32 MB
  unsigned* hb0   = (unsigned*)alloc((size_t)B_ * 256 * 4);   // 256 KB packed
  unsigned* hb1   = (unsigned*)alloc((size_t)B_ * 256 * 4);
  unsigned* flags = (unsigned*)alloc(8 * 4 * 32 * 32 * 4);    // 128 KB strided

  // flags gate all h reads -> zero every launch (graph replay safe)
  hipMemsetAsync(flags, 0, 8 * 4 * 32 * 32 * 4, stream);

  prep_w<<<dim3(16, 32), 256, 0, stream>>>(Wx, Uh, Wt);
  stage_x<<<T_ * B_, 256, 0, stream>>>(captions, emb, xs);

  void* kargs[] = {(void*)&xs, (void*)&Wt, (void*)&bx, (void*)&bu,
                   (void*)&hb0, (void*)&hb1, (void*)&flags};
  hipLaunchCooperativeKernel((const void*)lstm_all, dim3(NB), dim3(NT),
                             kargs, 0, stream);

  // t=127 wrote buffer 127&1 = hb1
  final_fc<<<B_, 256, 0, stream>>>(hb1, fcW, fcb, out);
}

// Round 15
// 685.751 us; speedup vs baseline: 1.0994x; 1.0994x over previous
//
#include <hip/hip_runtime.h>

#define B_ 256
#define T_ 128
#define E_ 512
#define H_ 512
#define NG 2048   // 4*H_
#define NB 256    // persistent blocks
#define NT 512    // threads per block (8 waves)

typedef __attribute__((ext_vector_type(8))) short bf16x8;
typedef __attribute__((ext_vector_type(4))) float f32x4;
typedef unsigned long long u64;

__device__ __forceinline__ short f2bf(float f) {
  union { float f; unsigned u; } x; x.f = f;
  unsigned r = x.u + 0x7FFFu + ((x.u >> 16) & 1u);  // RNE
  return (short)(r >> 16);
}
__device__ __forceinline__ float bf2f(short s) {
  union { unsigned u; float f; } x;
  x.u = ((unsigned)(unsigned short)s) << 16; return x.f;
}
__device__ __forceinline__ float sigm(float x) { return 1.0f / (1.0f + __expf(-x)); }
__device__ __forceinline__ float tanh_(float x) {
  float cx = fminf(fmaxf(x, -9.f), 9.f);
  float e = __expf(2.f * cx);
  return (e - 1.f) / (e + 1.f);
}

// ---- Wt[j][k] = bf16( k<512 ? Wx[k][j] : Uh[k-512][j] )
__global__ __launch_bounds__(256) void prep_w(const float* __restrict__ Wx,
                                              const float* __restrict__ Uh,
                                              short* __restrict__ Wt) {
  __shared__ float tile[64][65];
  const int k0 = blockIdx.x * 64;   // 16 blocks
  const int j0 = blockIdx.y * 64;   // 32 blocks
  const int tx = threadIdx.x & 63, ty = threadIdx.x >> 6;
#pragma unroll
  for (int r = 0; r < 16; ++r) {
    int k = k0 + r * 4 + ty;
    float v = (k < 512) ? Wx[(size_t)k * NG + j0 + tx]
                        : Uh[(size_t)(k - 512) * NG + j0 + tx];
    tile[r * 4 + ty][tx] = v;
  }
  __syncthreads();
#pragma unroll
  for (int r = 0; r < 16; ++r) {
    int j = j0 + r * 4 + ty;
    Wt[(size_t)j * 1024 + k0 + tx] = f2bf(tile[tx][r * 4 + ty]);
  }
}

// ---- xs[t][b][e] = bf16(emb[captions[b][t]][e]); padding_idx=0 row zeroed
__global__ __launch_bounds__(256) void stage_x(const int* __restrict__ captions,
                                               const float* __restrict__ emb,
                                               short* __restrict__ xs) {
  const int bid = blockIdx.x;          // = t*B_ + b
  const int t = bid >> 8, b = bid & 255;
  const int tok = captions[b * T_ + t];
  short* o = xs + (size_t)bid * E_;
  const float* src = emb + (size_t)tok * E_;
  int e0 = threadIdx.x, e1 = threadIdx.x + 256;
  if (tok) { o[e0] = f2bf(src[e0]); o[e1] = f2bf(src[e1]); }
  else     { o[e0] = 0;             o[e1] = 0; }
}

// ---- persistent kernel: all 128 LSTM steps.  FAN-IN-16 GEOMETRY.
// grid 256 = 16 m-groups (mg = bid>>4, 16 batch rows) x 16 j-tiles (jt =
// bid&15, 32 hidden cols). Consecutive bids per group -> spread across XCDs.
// No B duplication across m-halves, so per-wave weights stay 128 VGPRs while
// each block covers 2x the hidden cols -> groups of 16 blocks (convoy halved),
// reader slices span 8 writer blocks (fan halved).
// Waves (kq = wid>>1, jh = wid&1): kq0/1 = x K-halves, kq2/3 = h K-halves;
// jh = hidden sub-slice (16 cols). Protocol = R10 verbatim: phase A computes,
// partials (kq0,1,3) -> parity LDS, lgkmcnt(0), raw s_barrier; phase B: kq2
// waves reduce in regs + gates (c in regs) + packed-u32 h store + vmcnt(0)
// ACK + per-wave flag (one 128-B line each). Readers poll 16 flag lines
// (8 writer blocks x 2 publisher waves), then one bulk u64 load pass.
// Overwrite safety (2 buffers): flag=t+1 from Y implies Y passed barrier(t),
// hence Y consumed h_{t-1}; X stores h_{t+1} (same buffer) only after its kq2
// AND kq3 saw all slice flags >= t+1 (barrier-ordered). Flags zeroed per launch.
__global__ __launch_bounds__(NT, 2) void lstm_all(
    const short* __restrict__ xs,   // [T][B][E] bf16
    const short* __restrict__ Wt,   // [2048][1024] bf16
    const float* __restrict__ bx, const float* __restrict__ bu,
    unsigned* __restrict__ hb0, unsigned* __restrict__ hb1,
    unsigned* __restrict__ flags) { // [16 mg][2 jh][16 jt] stride 32 uints
  // [parity][slot(kq0,kq1,kq3)][jh][gate][l4][l15] of f32x4 -> 48 KB
  __shared__ f32x4 part[2][3][2][4][4][16];

  const int tid = threadIdx.x;
  const int wid = tid >> 6, lane = tid & 63;
  const int l15 = lane & 15, l4 = lane >> 4;
  const int kq = wid >> 1, jh = wid & 1;
  const int mg = blockIdx.x >> 4, jt = blockIdx.x & 15;
  const int j0 = jt * 32;                 // 32 hidden cols per block
  const int rA = mg * 16 + l15;           // 16 batch rows per block

  // ---- persistent B fragments, pinned on-chip (VGPR/AGPR)
  bf16x8 bfr[4][8];
#pragma unroll
  for (int g = 0; g < 4; ++g) {
    const short* wp = Wt + (size_t)(g * 512 + j0 + jh * 16 + l15) * 1024
                         + kq * 256 + l4 * 8;
#pragma unroll
    for (int ks = 0; ks < 8; ++ks)
      bfr[g][ks] = *(const bf16x8*)(wp + ks * 32);
  }
#pragma unroll
  for (int g = 0; g < 4; ++g)
#pragma unroll
    for (int ks = 0; ks < 8; ++ks)
      asm volatile("" : "+v"(bfr[g][ks]));   // sever rematerialization

  // ---- kq2 gate constants: lane owns col J, rows l4*4+r (4 cells)
  const int J = j0 + jh * 16 + l15;
  const float bi  = bx[J] + bu[J];
  const float bf_ = bx[512 + J] + bu[512 + J];
  const float bo  = bx[1024 + J] + bu[1024 + J];
  const float bg  = bx[1536 + J] + bu[1536 + J];
  float c_reg[4] = {0.f, 0.f, 0.f, 0.f};

  unsigned* fl = flags + mg * 1024;   // flag (jh,jt) at fl[(jh*16+jt)*32]

  for (int t = 0; t < T_; ++t) {
    const int tp = t & 1;
    unsigned* hout = tp ? hb1 : hb0;
    const unsigned* hin = tp ? hb0 : hb1;   // h_{t-1} in buffer (t-1)&1

    f32x4 acc[4] = {{0,0,0,0},{0,0,0,0},{0,0,0,0},{0,0,0,0}};

    if (kq < 2) {
      // ---- x half of K (always ready)
      const short* ab = xs + ((size_t)t * B_ + rA) * E_ + kq * 256 + l4 * 8;
      bf16x8 af[8];
#pragma unroll
      for (int ks = 0; ks < 8; ++ks) af[ks] = *(const bf16x8*)(ab + ks * 32);
#pragma unroll
      for (int ks = 0; ks < 8; ++ks)
#pragma unroll
        for (int g = 0; g < 4; ++g)
          acc[g] = __builtin_amdgcn_mfma_f32_16x16x32_bf16(af[ks], bfr[g][ks], acc[g], 0, 0, 0);
    } else if (t > 0) {
      // ---- poll the 16 publisher flags of this slice: 8 writer blocks x 2 jh
      const unsigned thr = (unsigned)t;
      const int jtp = (kq - 2) * 8 + (lane >> 1 & 7);   // writer j-tile
      const int jhp = lane & 1;                          // writer jh wave
      const unsigned* myfl = fl + (jhp * 16 + jtp) * 32;
      unsigned v = __hip_atomic_load(myfl, __ATOMIC_RELAXED, __HIP_MEMORY_SCOPE_AGENT);
      int spin = 0;
      while (!__all((int)((lane >= 16) | (v >= thr)))) {
        if (spin++ < 4) __builtin_amdgcn_s_sleep(1);
        else            __builtin_amdgcn_s_sleep(8);
        v = __hip_atomic_load(myfl, __ATOMIC_RELAXED, __HIP_MEMORY_SCOPE_AGENT);
      }
      asm volatile("" ::: "memory");
      // ---- one bulk load pass (flags are ack-gated: data valid), then MFMA
      const u64* hp = (const u64*)hin + (size_t)rA * 128 + (kq - 2) * 64 + l4 * 2;
      u64 w[16];
#pragma unroll
      for (int ks = 0; ks < 8; ++ks) {
        w[ks * 2]     = __hip_atomic_load(hp + ks * 8,     __ATOMIC_RELAXED, __HIP_MEMORY_SCOPE_AGENT);
        w[ks * 2 + 1] = __hip_atomic_load(hp + ks * 8 + 1, __ATOMIC_RELAXED, __HIP_MEMORY_SCOPE_AGENT);
      }
#pragma unroll
      for (int ks = 0; ks < 8; ++ks) {
        union { bf16x8 v; unsigned u[4]; } fa;
        fa.u[0] = (unsigned)w[ks * 2];
        fa.u[1] = (unsigned)(w[ks * 2] >> 32);
        fa.u[2] = (unsigned)w[ks * 2 + 1];
        fa.u[3] = (unsigned)(w[ks * 2 + 1] >> 32);
#pragma unroll
        for (int g = 0; g < 4; ++g)
          acc[g] = __builtin_amdgcn_mfma_f32_16x16x32_bf16(fa.v, bfr[g][ks], acc[g], 0, 0, 0);
      }
    }
    // (kq>=2, t==0: h_{-1}=0 -> acc stays 0)

    // ---- partials to parity LDS slot (one ds_write_b128 per gate);
    //      kq2 keeps its partial in registers
    if (kq != 2) {
      const int slot = (kq == 3) ? 2 : kq;
#pragma unroll
      for (int g = 0; g < 4; ++g)
        part[tp][slot][jh][g][l4][l15] = acc[g];
    }
    asm volatile("s_waitcnt lgkmcnt(0)" ::: "memory");
    __builtin_amdgcn_s_barrier();               // raw barrier: no vmcnt drain

    // ---- phase B: kq2 waves finalize; others run ahead into t+1
    if (kq == 2) {
#pragma unroll
      for (int g = 0; g < 4; ++g)
        acc[g] += part[tp][0][jh][g][l4][l15]
                + part[tp][1][jh][g][l4][l15]
                + part[tp][2][jh][g][l4][l15];
      unsigned hw[4];
#pragma unroll
      for (int r = 0; r < 4; ++r) {
        float iv = acc[0][r] + bi, fv = acc[1][r] + bf_;
        float ov = acc[2][r] + bo, gv = acc[3][r] + bg;
        float cn = sigm(fv) * c_reg[r] + sigm(iv) * tanh_(gv);
        c_reg[r] = cn;
        hw[r] = (unsigned)(unsigned short)f2bf(sigm(ov) * tanh_(cn));
      }
#pragma unroll
      for (int r = 0; r < 4; ++r) {
        unsigned other = (unsigned)__shfl_xor((int)hw[r], 1, 64);
        if (!(l15 & 1)) {
          const int R = mg * 16 + l4 * 4 + r;
          __hip_atomic_store(hout + (size_t)R * 256 + (J >> 1),
                             hw[r] | (other << 16),
                             __ATOMIC_RELAXED, __HIP_MEMORY_SCOPE_AGENT);
        }
      }
      // ACK then flag: readers that see the flag see the data (R10 protocol).
      asm volatile("s_waitcnt vmcnt(0)" ::: "memory");
      if (lane == 0)
        __hip_atomic_store(fl + (jh * 16 + jt) * 32, (unsigned)(t + 1),
                           __ATOMIC_RELAXED, __HIP_MEMORY_SCOPE_AGENT);
    }
  }
}

// ---- out[b,:] = normalize( h_last[b,:] @ fcW + fcb ); h is packed u32{2xbf16}
__global__ __launch_bounds__(256) void final_fc(const unsigned* __restrict__ h,
                                                const float* __restrict__ fcW,
                                                const float* __restrict__ fcb,
                                                float* __restrict__ out) {
  const int b = blockIdx.x, tid = threadIdx.x;
  __shared__ float hrow[512];
  __shared__ float red[256];
  {
    unsigned w = h[(size_t)b * 256 + tid];
    hrow[tid * 2]     = bf2f((short)(w & 0xFFFF));
    hrow[tid * 2 + 1] = bf2f((short)(w >> 16));
  }
  __syncthreads();
  float a0 = fcb[tid], a1 = fcb[tid + 256];
  for (int k = 0; k < 512; ++k) {
    float hv = hrow[k];
    a0 += hv * fcW[(size_t)k * 512 + tid];
    a1 += hv * fcW[(size_t)k * 512 + tid + 256];
  }
  red[tid] = a0 * a0 + a1 * a1;
  __syncthreads();
  for (int s = 128; s > 0; s >>= 1) {
    if (tid < s) red[tid] += red[tid + s];
    __syncthreads();
  }
  float scale = 1.0f / fmaxf(sqrtf(red[0]), 1e-12f);
  out[(size_t)b * 512 + tid] = a0 * scale;
  out[(size_t)b * 512 + tid + 256] = a1 * scale;
}

extern "C" void kernel_launch(void* const* d_in, const int* in_sizes, int n_in,
                              void* d_out, int out_size, void* d_ws, size_t ws_size,
                              hipStream_t stream) {
  const int*   captions = (const int*)d_in[0];
  const float* emb      = (const float*)d_in[1];
  const float* Wx       = (const float*)d_in[2];
  const float* bx       = (const float*)d_in[3];
  const float* Uh       = (const float*)d_in[4];
  const float* bu       = (const float*)d_in[5];
  const float* fcW      = (const float*)d_in[6];
  const float* fcb      = (const float*)d_in[7];
  float* out = (float*)d_out;

  char* ws = (char*)d_ws;
  size_t off = 0;
  auto alloc = [&](size_t bytes) {
    char* p = ws + off;
    off += (bytes + 255) & ~(size_t)255;
    return p;
  };
  short*    Wt    = (short*)alloc((size_t)NG * 1024 * 2);     // 4 MB
  short*    xs    = (short*)alloc((size_t)T_ * B_ * E_ * 2);  // 32 MB
  unsigned* hb0   = (unsigned*)alloc((size_t)B_ * 256 * 4);   // 256 KB packed
  unsigned* hb1   = (unsigned*)alloc((size_t)B_ * 256 * 4);
  unsigned* flags = (unsigned*)alloc(16 * 2 * 16 * 32 * 4);   // 64 KB strided

  // flags gate all h reads -> zero every launch (graph replay safe)
  hipMemsetAsync(flags, 0, 16 * 2 * 16 * 32 * 4, stream);

  prep_w<<<dim3(16, 32), 256, 0, stream>>>(Wx, Uh, Wt);
  stage_x<<<T_ * B_, 256, 0, stream>>>(captions, emb, xs);

  void* kargs[] = {(void*)&xs, (void*)&Wt, (void*)&bx, (void*)&bu,
                   (void*)&hb0, (void*)&hb1, (void*)&flags};
  hipLaunchCooperativeKernel((const void*)lstm_all, dim3(NB), dim3(NT),
                             kargs, 0, stream);

  // t=127 wrote buffer 127&1 = hb1
  final_fc<<<B_, 256, 0, stream>>>(hb1, fcW, fcb, out);
}

// Round 16
// 684.235 us; speedup vs baseline: 1.1018x; 1.0022x over previous
//
#include <hip/hip_runtime.h>

#define B_ 256
#define T_ 128
#define E_ 512
#define H_ 512
#define NG 2048   // 4*H_
#define NB 256    // persistent blocks
#define NT 512    // threads per block (8 waves)

typedef __attribute__((ext_vector_type(8))) short bf16x8;
typedef __attribute__((ext_vector_type(4))) float f32x4;
typedef unsigned long long u64;

__device__ __forceinline__ short f2bf(float f) {
  union { float f; unsigned u; } x; x.f = f;
  unsigned r = x.u + 0x7FFFu + ((x.u >> 16) & 1u);  // RNE
  return (short)(r >> 16);
}
__device__ __forceinline__ float bf2f(short s) {
  union { unsigned u; float f; } x;
  x.u = ((unsigned)(unsigned short)s) << 16; return x.f;
}
__device__ __forceinline__ float sigm(float x) { return 1.0f / (1.0f + __expf(-x)); }
__device__ __forceinline__ float tanh_(float x) {
  float cx = fminf(fmaxf(x, -9.f), 9.f);
  float e = __expf(2.f * cx);
  return (e - 1.f) / (e + 1.f);
}

// ---- Wt[j][k] = bf16( k<512 ? Wx[k][j] : Uh[k-512][j] )
__global__ __launch_bounds__(256) void prep_w(const float* __restrict__ Wx,
                                              const float* __restrict__ Uh,
                                              short* __restrict__ Wt) {
  __shared__ float tile[64][65];
  const int k0 = blockIdx.x * 64;   // 16 blocks
  const int j0 = blockIdx.y * 64;   // 32 blocks
  const int tx = threadIdx.x & 63, ty = threadIdx.x >> 6;
#pragma unroll
  for (int r = 0; r < 16; ++r) {
    int k = k0 + r * 4 + ty;
    float v = (k < 512) ? Wx[(size_t)k * NG + j0 + tx]
                        : Uh[(size_t)(k - 512) * NG + j0 + tx];
    tile[r * 4 + ty][tx] = v;
  }
  __syncthreads();
#pragma unroll
  for (int r = 0; r < 16; ++r) {
    int j = j0 + r * 4 + ty;
    Wt[(size_t)j * 1024 + k0 + tx] = f2bf(tile[tx][r * 4 + ty]);
  }
}

// ---- xs[t][b][e] = bf16(emb[captions[b][t]][e]); padding_idx=0 row zeroed
// grid-stride: 2048 blocks handle 32768 (t,b) pairs
__global__ __launch_bounds__(256) void stage_x(const int* __restrict__ captions,
                                               const float* __restrict__ emb,
                                               short* __restrict__ xs) {
  for (int bid = blockIdx.x; bid < T_ * B_; bid += 2048) {
    const int t = bid >> 8, b = bid & 255;
    const int tok = captions[b * T_ + t];
    short* o = xs + (size_t)bid * E_;
    const float* src = emb + (size_t)tok * E_;
    int e0 = threadIdx.x, e1 = threadIdx.x + 256;
    if (tok) { o[e0] = f2bf(src[e0]); o[e1] = f2bf(src[e1]); }
    else     { o[e0] = 0;             o[e1] = 0; }
  }
}

// ---- persistent kernel: all 128 LSTM steps.  FAN-IN-16 GEOMETRY (R14, proven).
// grid 256 = 16 m-groups (mg = bid>>4, 16 batch rows) x 16 j-tiles (jt =
// bid&15, 32 hidden cols). Consecutive bids per group -> spread across XCDs.
// Waves (kq = wid>>1, jh = wid&1): kq0/1 = x K-halves, kq2/3 = h K-halves;
// jh = hidden sub-slice (16 cols). Protocol: phase A computes, partials
// (kq0,1,3) -> parity LDS, lgkmcnt(0), raw s_barrier; phase B: kq2 waves
// reduce in regs + gates (c in regs) + packed-u32 h store + vmcnt(0) ACK +
// per-wave flag (one 128-B line each). Readers poll 16 flag lines (8 writer
// blocks x 2 publisher waves), then one bulk u64 load pass.
// Overwrite safety (2 buffers): flag=t+1 from Y implies Y passed barrier(t),
// hence Y consumed h_{t-1}; X stores h_{t+1} (same buffer) only after its kq2
// AND kq3 saw all slice flags >= t+1 (barrier-ordered). Flags zeroed per launch.
__global__ __launch_bounds__(NT, 2) void lstm_all(
    const short* __restrict__ xs,   // [T][B][E] bf16
    const short* __restrict__ Wt,   // [2048][1024] bf16
    const float* __restrict__ bx, const float* __restrict__ bu,
    unsigned* __restrict__ hb0, unsigned* __restrict__ hb1,
    unsigned* __restrict__ flags) { // [16 mg][2 jh][16 jt] stride 32 uints
  // [parity][slot(kq0,kq1,kq3)][jh][gate][l4][l15] of f32x4 -> 48 KB
  __shared__ f32x4 part[2][3][2][4][4][16];

  const int tid = threadIdx.x;
  const int wid = tid >> 6, lane = tid & 63;
  const int l15 = lane & 15, l4 = lane >> 4;
  const int kq = wid >> 1, jh = wid & 1;
  const int mg = blockIdx.x >> 4, jt = blockIdx.x & 15;
  const int j0 = jt * 32;                 // 32 hidden cols per block
  const int rA = mg * 16 + l15;           // 16 batch rows per block

  // ---- persistent B fragments, pinned on-chip (VGPR/AGPR)
  bf16x8 bfr[4][8];
#pragma unroll
  for (int g = 0; g < 4; ++g) {
    const short* wp = Wt + (size_t)(g * 512 + j0 + jh * 16 + l15) * 1024
                         + kq * 256 + l4 * 8;
#pragma unroll
    for (int ks = 0; ks < 8; ++ks)
      bfr[g][ks] = *(const bf16x8*)(wp + ks * 32);
  }
#pragma unroll
  for (int g = 0; g < 4; ++g)
#pragma unroll
    for (int ks = 0; ks < 8; ++ks)
      asm volatile("" : "+v"(bfr[g][ks]));   // sever rematerialization

  // ---- kq2 gate constants: lane owns col J, rows l4*4+r (4 cells)
  const int J = j0 + jh * 16 + l15;
  const float bi  = bx[J] + bu[J];
  const float bf_ = bx[512 + J] + bu[512 + J];
  const float bo  = bx[1024 + J] + bu[1024 + J];
  const float bg  = bx[1536 + J] + bu[1536 + J];
  float c_reg[4] = {0.f, 0.f, 0.f, 0.f};

  unsigned* fl = flags + mg * 1024;   // flag (jh,jt) at fl[(jh*16+jt)*32]

  for (int t = 0; t < T_; ++t) {
    const int tp = t & 1;
    unsigned* hout = tp ? hb1 : hb0;
    const unsigned* hin = tp ? hb0 : hb1;   // h_{t-1} in buffer (t-1)&1

    f32x4 acc[4] = {{0,0,0,0},{0,0,0,0},{0,0,0,0},{0,0,0,0}};

    if (kq < 2) {
      // ---- x half of K (always ready)
      const short* ab = xs + ((size_t)t * B_ + rA) * E_ + kq * 256 + l4 * 8;
      bf16x8 af[8];
#pragma unroll
      for (int ks = 0; ks < 8; ++ks) af[ks] = *(const bf16x8*)(ab + ks * 32);
#pragma unroll
      for (int ks = 0; ks < 8; ++ks)
#pragma unroll
        for (int g = 0; g < 4; ++g)
          acc[g] = __builtin_amdgcn_mfma_f32_16x16x32_bf16(af[ks], bfr[g][ks], acc[g], 0, 0, 0);
    } else if (t > 0) {
      // ---- poll the 16 publisher flags of this slice: 8 writer blocks x 2 jh
      const unsigned thr = (unsigned)t;
      const int jtp = (kq - 2) * 8 + (lane >> 1 & 7);   // writer j-tile
      const int jhp = lane & 1;                          // writer jh wave
      const unsigned* myfl = fl + (jhp * 16 + jtp) * 32;
      unsigned v = __hip_atomic_load(myfl, __ATOMIC_RELAXED, __HIP_MEMORY_SCOPE_AGENT);
      int spin = 0;
      while (!__all((int)((lane >= 16) | (v >= thr)))) {
        if (spin++ < 4) __builtin_amdgcn_s_sleep(1);
        else            __builtin_amdgcn_s_sleep(2);   // finer discovery quantum
        v = __hip_atomic_load(myfl, __ATOMIC_RELAXED, __HIP_MEMORY_SCOPE_AGENT);
      }
      asm volatile("" ::: "memory");
      // ---- one bulk load pass (flags are ack-gated: data valid), then MFMA
      const u64* hp = (const u64*)hin + (size_t)rA * 128 + (kq - 2) * 64 + l4 * 2;
      u64 w[16];
#pragma unroll
      for (int ks = 0; ks < 8; ++ks) {
        w[ks * 2]     = __hip_atomic_load(hp + ks * 8,     __ATOMIC_RELAXED, __HIP_MEMORY_SCOPE_AGENT);
        w[ks * 2 + 1] = __hip_atomic_load(hp + ks * 8 + 1, __ATOMIC_RELAXED, __HIP_MEMORY_SCOPE_AGENT);
      }
#pragma unroll
      for (int ks = 0; ks < 8; ++ks) {
        union { bf16x8 v; unsigned u[4]; } fa;
        fa.u[0] = (unsigned)w[ks * 2];
        fa.u[1] = (unsigned)(w[ks * 2] >> 32);
        fa.u[2] = (unsigned)w[ks * 2 + 1];
        fa.u[3] = (unsigned)(w[ks * 2 + 1] >> 32);
#pragma unroll
        for (int g = 0; g < 4; ++g)
          acc[g] = __builtin_amdgcn_mfma_f32_16x16x32_bf16(fa.v, bfr[g][ks], acc[g], 0, 0, 0);
      }
    }
    // (kq>=2, t==0: h_{-1}=0 -> acc stays 0)

    // ---- partials to parity LDS slot (one ds_write_b128 per gate);
    //      kq2 keeps its partial in registers
    if (kq != 2) {
      const int slot = (kq == 3) ? 2 : kq;
#pragma unroll
      for (int g = 0; g < 4; ++g)
        part[tp][slot][jh][g][l4][l15] = acc[g];
    }
    asm volatile("s_waitcnt lgkmcnt(0)" ::: "memory");
    __builtin_amdgcn_s_barrier();               // raw barrier: no vmcnt drain

    // ---- phase B: kq2 waves finalize; others run ahead into t+1
    if (kq == 2) {
#pragma unroll
      for (int g = 0; g < 4; ++g)
        acc[g] += part[tp][0][jh][g][l4][l15]
                + part[tp][1][jh][g][l4][l15]
                + part[tp][2][jh][g][l4][l15];
      unsigned hw[4];
#pragma unroll
      for (int r = 0; r < 4; ++r) {
        float iv = acc[0][r] + bi, fv = acc[1][r] + bf_;
        float ov = acc[2][r] + bo, gv = acc[3][r] + bg;
        float cn = sigm(fv) * c_reg[r] + sigm(iv) * tanh_(gv);
        c_reg[r] = cn;
        hw[r] = (unsigned)(unsigned short)f2bf(sigm(ov) * tanh_(cn));
      }
#pragma unroll
      for (int r = 0; r < 4; ++r) {
        unsigned other = (unsigned)__shfl_xor((int)hw[r], 1, 64);
        if (!(l15 & 1)) {
          const int R = mg * 16 + l4 * 4 + r;
          __hip_atomic_store(hout + (size_t)R * 256 + (J >> 1),
                             hw[r] | (other << 16),
                             __ATOMIC_RELAXED, __HIP_MEMORY_SCOPE_AGENT);
        }
      }
      // ACK then flag: readers that see the flag see the data (R10 protocol).
      asm volatile("s_waitcnt vmcnt(0)" ::: "memory");
      if (lane == 0)
        __hip_atomic_store(fl + (jh * 16 + jt) * 32, (unsigned)(t + 1),
                           __ATOMIC_RELAXED, __HIP_MEMORY_SCOPE_AGENT);
    }
  }
}

// ---- out[b,:] = normalize( h_last[b,:] @ fcW + fcb ); h packed u32{2xbf16}.
// 4 rows per block (64 blocks): fcW read once per 4 rows -> 64 MB total L3
// traffic instead of 256 MB. Row norm stays block-local.
__global__ __launch_bounds__(256) void final_fc(const unsigned* __restrict__ h,
                                                const float* __restrict__ fcW,
                                                const float* __restrict__ fcb,
                                                float* __restrict__ out) {
  const int b0 = blockIdx.x * 4, tid = threadIdx.x;
  __shared__ float hrow[4][512];
  __shared__ float red[4][256];
  for (int i = tid; i < 1024; i += 256) {
    unsigned w = h[(size_t)(b0 + (i >> 8)) * 256 + (i & 255)];
    hrow[i >> 8][(i & 255) * 2]     = bf2f((short)(w & 0xFFFF));
    hrow[i >> 8][(i & 255) * 2 + 1] = bf2f((short)(w >> 16));
  }
  __syncthreads();
  float a0[4], a1[4];
#pragma unroll
  for (int r = 0; r < 4; ++r) { a0[r] = fcb[tid]; a1[r] = fcb[tid + 256]; }
  for (int k = 0; k < 512; ++k) {
    const float w0 = fcW[(size_t)k * 512 + tid];
    const float w1 = fcW[(size_t)k * 512 + tid + 256];
#pragma unroll
    for (int r = 0; r < 4; ++r) {
      a0[r] += hrow[r][k] * w0;
      a1[r] += hrow[r][k] * w1;
    }
  }
#pragma unroll
  for (int r = 0; r < 4; ++r) red[r][tid] = a0[r] * a0[r] + a1[r] * a1[r];
  __syncthreads();
  for (int s = 128; s > 0; s >>= 1) {
    if (tid < s) {
#pragma unroll
      for (int r = 0; r < 4; ++r) red[r][tid] += red[r][tid + s];
    }
    __syncthreads();
  }
#pragma unroll
  for (int r = 0; r < 4; ++r) {
    const float scale = 1.0f / fmaxf(sqrtf(red[r][0]), 1e-12f);
    out[(size_t)(b0 + r) * 512 + tid]       = a0[r] * scale;
    out[(size_t)(b0 + r) * 512 + tid + 256] = a1[r] * scale;
  }
}

extern "C" void kernel_launch(void* const* d_in, const int* in_sizes, int n_in,
                              void* d_out, int out_size, void* d_ws, size_t ws_size,
                              hipStream_t stream) {
  const int*   captions = (const int*)d_in[0];
  const float* emb      = (const float*)d_in[1];
  const float* Wx       = (const float*)d_in[2];
  const float* bx       = (const float*)d_in[3];
  const float* Uh       = (const float*)d_in[4];
  const float* bu       = (const float*)d_in[5];
  const float* fcW      = (const float*)d_in[6];
  const float* fcb      = (const float*)d_in[7];
  float* out = (float*)d_out;

  char* ws = (char*)d_ws;
  size_t off = 0;
  auto alloc = [&](size_t bytes) {
    char* p = ws + off;
    off += (bytes + 255) & ~(size_t)255;
    return p;
  };
  short*    Wt    = (short*)alloc((size_t)NG * 1024 * 2);     // 4 MB
  short*    xs    = (short*)alloc((size_t)T_ * B_ * E_ * 2);  // 32 MB
  unsigned* hb0   = (unsigned*)alloc((size_t)B_ * 256 * 4);   // 256 KB packed
  unsigned* hb1   = (unsigned*)alloc((size_t)B_ * 256 * 4);
  unsigned* flags = (unsigned*)alloc(16 * 2 * 16 * 32 * 4);   // 64 KB strided

  // flags gate all h reads -> zero every launch (graph replay safe)
  hipMemsetAsync(flags, 0, 16 * 2 * 16 * 32 * 4, stream);

  prep_w<<<dim3(16, 32), 256, 0, stream>>>(Wx, Uh, Wt);
  stage_x<<<2048, 256, 0, stream>>>(captions, emb, xs);

  void* kargs[] = {(void*)&xs, (void*)&Wt, (void*)&bx, (void*)&bu,
                   (void*)&hb0, (void*)&hb1, (void*)&flags};
  hipLaunchCooperativeKernel((const void*)lstm_all, dim3(NB), dim3(NT),
                             kargs, 0, stream);

  // t=127 wrote buffer 127&1 = hb1
  final_fc<<<64, 256, 0, stream>>>(hb1, fcW, fcb, out);
}